// Round 14
// baseline (1890.729 us; speedup 1.0000x reference)
//
#include <hip/hip_runtime.h>

#define NROWS 65536
#define SB 256  // stride of the main ws activation buffer

__device__ __forceinline__ float frelu(float v) { return fmaxf(v, 0.f); }

// ---------------- ws layout (floats, relative to weight region W) ----------------
#define OFF_WT1   0        // [168][128]  enc_w1^T
#define OFF_WT2   21504    // [128][256]  enc_w2^T
#define OFF_WT3   54272    // [256][256]  enc_w3^T
#define OFF_WTQ   119808   // [256][64]   q_w^T
#define OFF_WTD1  136192   // [64][256]   dec_w1^T
#define OFF_WTD2  152576   // [256][128]  dec_w2^T
#define OFF_WTD3  185344   // [128][256]  dec_w3^T (o>=165 zero-padded)
#define OFF_WAPE  218112   // [2][64][32][4] enc_res_wa packed
#define OFF_WBTE  234496   // [2][32][256]   enc_res_wb^T
#define OFF_WAPD  250880   // [2][64][32][4] dec_res_wa packed
#define OFF_WBTD  267264   // [2][32][256]   dec_res_wb^T
#define OFF_ETG   283648   // [4][512][64]  codebook row-major
#define OFF_EN2   414720   // [4][512]      ||e_k||^2
#define OFF_DSUM  416768   // [1]
#define PREP_N    416769

// ---------------- fused prep kernel ----------------
__global__ void prep_k(const float* __restrict__ ew1, const float* __restrict__ ew2,
                       const float* __restrict__ ew3, const float* __restrict__ qw,
                       const float* __restrict__ dw1, const float* __restrict__ dw2,
                       const float* __restrict__ dw3, const float* __restrict__ ewa,
                       const float* __restrict__ ewb, const float* __restrict__ dwa,
                       const float* __restrict__ dwb, const float* __restrict__ embeds,
                       float* __restrict__ W) {
  int idx = blockIdx.x * 256 + threadIdx.x;
  if (idx < 21504) {  // wT1 [168][128] <- ew1 [128][165]
    int k = idx >> 7, o = idx & 127;
    W[OFF_WT1 + idx] = (k < 165) ? ew1[o * 165 + k] : 0.f;
    return;
  }
  idx -= 21504;
  if (idx < 32768) {  // wT2 [128][256]
    int k = idx >> 8, o = idx & 255;
    W[OFF_WT2 + idx] = ew2[o * 128 + k];
    return;
  }
  idx -= 32768;
  if (idx < 65536) {  // wT3 [256][256]
    int k = idx >> 8, o = idx & 255;
    W[OFF_WT3 + idx] = ew3[o * 256 + k];
    return;
  }
  idx -= 65536;
  if (idx < 16384) {  // wTq [256][64]
    int k = idx >> 6, o = idx & 63;
    W[OFF_WTQ + idx] = qw[o * 256 + k];
    return;
  }
  idx -= 16384;
  if (idx < 16384) {  // wTd1 [64][256]
    int k = idx >> 8, o = idx & 255;
    W[OFF_WTD1 + idx] = dw1[o * 64 + k];
    return;
  }
  idx -= 16384;
  if (idx < 32768) {  // wTd2 [256][128]
    int k = idx >> 7, o = idx & 127;
    W[OFF_WTD2 + idx] = dw2[o * 256 + k];
    return;
  }
  idx -= 32768;
  if (idx < 32768) {  // wTd3 [128][256], pad o>=165
    int k = idx >> 8, o = idx & 255;
    W[OFF_WTD3 + idx] = (o < 165) ? dw3[o * 128 + k] : 0.f;
    return;
  }
  idx -= 32768;
  if (idx < 16384) {  // waPe
    int l = idx >> 13, rem = idx & 8191;
    int k4 = rem >> 7, rem2 = rem & 127, o = rem2 >> 2, kk = rem2 & 3;
    W[OFF_WAPE + idx] = ewa[l * 8192 + o * 256 + k4 * 4 + kk];
    return;
  }
  idx -= 16384;
  if (idx < 16384) {  // wbTe
    int l = idx >> 13, rem = idx & 8191;
    int k = rem >> 8, o = rem & 255;
    W[OFF_WBTE + idx] = ewb[l * 8192 + o * 32 + k];
    return;
  }
  idx -= 16384;
  if (idx < 16384) {  // waPd
    int l = idx >> 13, rem = idx & 8191;
    int k4 = rem >> 7, rem2 = rem & 127, o = rem2 >> 2, kk = rem2 & 3;
    W[OFF_WAPD + idx] = dwa[l * 8192 + o * 256 + k4 * 4 + kk];
    return;
  }
  idx -= 16384;
  if (idx < 16384) {  // wbTd
    int l = idx >> 13, rem = idx & 8191;
    int k = rem >> 8, o = rem & 255;
    W[OFF_WBTD + idx] = dwb[l * 8192 + o * 32 + k];
    return;
  }
  idx -= 16384;
  if (idx < 131072) {  // etg[l][k][d]
    int d = idx & 63, k = (idx >> 6) & 511, l = idx >> 15;
    W[OFF_ETG + idx] = embeds[(l * 64 + d) * 512 + k];
    return;
  }
  idx -= 131072;
  if (idx < 2048) {  // en2
    int l = idx >> 9, k = idx & 511;
    float s = 0.f;
    for (int d = 0; d < 64; ++d) {
      float e = embeds[(l * 64 + d) * 512 + k];
      s = fmaf(e, e, s);
    }
    W[OFF_EN2 + idx] = s;
    return;
  }
  idx -= 2048;
  if (idx == 0) W[OFF_DSUM] = 0.f;
}

// ---------------- conv2_k: R6 proven form (LDS x-stage, lane=output) ----------------
template <int CIN, int CINP, int COUT, int CP, int INSTRIDE, int OUTSTRIDE, bool RELU_IN,
          bool RELU_OUT>
__global__ __launch_bounds__(256, 4) void conv2_k(const float* in, const float* __restrict__ wT,
                                                  const float* __restrict__ b, float* out) {
  constexpr int COUTP = 64 * CP;
  constexpr bool GUARD = (COUT != COUTP);
  typedef float vCP __attribute__((ext_vector_type(CP)));
  __shared__ float xs[32][CINP];
  const int tid = threadIdx.x, lane = tid & 63, wv = tid >> 6;
  const long row0 = (long)blockIdx.x * 32;

  for (int i = tid; i < 32 * CINP; i += 256) {
    const int r = i / CINP, c = i % CINP;
    float v = (CIN == CINP || c < CIN) ? in[(row0 + r) * (long)INSTRIDE + c] : 0.f;
    if (RELU_IN) v = frelu(v);
    xs[r][c] = v;
  }
  __syncthreads();

  float acc[8][CP];
#pragma unroll
  for (int i = 0; i < 8; ++i)
#pragma unroll
    for (int j = 0; j < CP; ++j) acc[i][j] = 0.f;

  const float* wbase = wT + lane * CP;
#pragma unroll 4
  for (int k0 = 0; k0 < CINP; k0 += 4) {
    vCP wk[4];
#pragma unroll
    for (int kk = 0; kk < 4; ++kk) wk[kk] = *(const vCP*)(wbase + (k0 + kk) * COUTP);
#pragma unroll
    for (int rj = 0; rj < 8; ++rj) {
      const float4 x = *(const float4*)(&xs[wv * 8 + rj][k0]);
#pragma unroll
      for (int j = 0; j < CP; ++j) {
        acc[rj][j] = fmaf(x.x, wk[0][j], acc[rj][j]);
        acc[rj][j] = fmaf(x.y, wk[1][j], acc[rj][j]);
        acc[rj][j] = fmaf(x.z, wk[2][j], acc[rj][j]);
        acc[rj][j] = fmaf(x.w, wk[3][j], acc[rj][j]);
      }
    }
  }

  float bias[CP];
#pragma unroll
  for (int j = 0; j < CP; ++j) {
    const int o = lane * CP + j;
    bias[j] = (!GUARD || o < COUT) ? b[o] : 0.f;
  }
#pragma unroll
  for (int rj = 0; rj < 8; ++rj) {
    const long rbase = (row0 + wv * 8 + rj) * (long)OUTSTRIDE;
    if constexpr (!GUARD) {
      vCP v;
#pragma unroll
      for (int j = 0; j < CP; ++j) {
        const float t = acc[rj][j] + bias[j];
        v[j] = RELU_OUT ? frelu(t) : t;
      }
      *(vCP*)(out + rbase + lane * CP) = v;
    } else {
#pragma unroll
      for (int j = 0; j < CP; ++j) {
        const int o = lane * CP + j;
        if (o < COUT) {
          const float t = acc[rj][j] + bias[j];
          out[rbase + o] = RELU_OUT ? frelu(t) : t;
        }
      }
    }
  }
}

// ---------------- conv6_k: per-tile TRANSPOSED x (lane = row), scalar weights --------
template <int CIN, int COUT, int COUTP, int INSTRIDE, int OUTSTRIDE, bool RELU_IN, bool RELU_OUT>
__global__ __launch_bounds__(512, 2) void conv6_k(const float* __restrict__ in,
                                                  const float* __restrict__ wT,
                                                  const float* __restrict__ b,
                                                  float* __restrict__ out) {
  constexpr int MAXD = (CIN > COUT) ? CIN : COUT;
  __shared__ float lds[MAXD * 65];
  const int tid = threadIdx.x;
  const int lane = tid & 63;
  const int wv = __builtin_amdgcn_readfirstlane(tid >> 6);
  const long row0 = (long)blockIdx.x * 64;

  constexpr int C4 = CIN / 4;
  for (int i = tid; i < 64 * C4; i += 512) {
    const int r = i / C4, c4 = i % C4;
    float4 v = *(const float4*)(in + (row0 + r) * (long)INSTRIDE + c4 * 4);
    if (RELU_IN) {
      v.x = frelu(v.x);
      v.y = frelu(v.y);
      v.z = frelu(v.z);
      v.w = frelu(v.w);
    }
    lds[(c4 * 4 + 0) * 65 + r] = v.x;
    lds[(c4 * 4 + 1) * 65 + r] = v.y;
    lds[(c4 * 4 + 2) * 65 + r] = v.z;
    lds[(c4 * 4 + 3) * 65 + r] = v.w;
  }
  __syncthreads();

  float acc[32];
#pragma unroll
  for (int j = 0; j < 32; ++j) acc[j] = 0.f;

  const float* wrow = wT + wv * 32;
#pragma unroll 2
  for (int k = 0; k < CIN; ++k) {
    const float xv = lds[k * 65 + lane];
    const float* wk = wrow + (long)k * COUTP;
#pragma unroll
    for (int j = 0; j < 32; ++j) acc[j] = fmaf(xv, wk[j], acc[j]);
  }

  const float* bb = b + wv * 32;
#pragma unroll
  for (int j = 0; j < 32; ++j) {
    float t = acc[j] + bb[j];
    acc[j] = RELU_OUT ? frelu(t) : t;
  }

  __syncthreads();
#pragma unroll
  for (int j = 0; j < 32; ++j) lds[(wv * 32 + j) * 65 + lane] = acc[j];
  __syncthreads();

  constexpr int O4 = COUT / 4;
  for (int i = tid; i < 64 * O4; i += 512) {
    const int r = i / O4, c4 = i % O4;
    float4 v;
    v.x = lds[(c4 * 4 + 0) * 65 + r];
    v.y = lds[(c4 * 4 + 1) * 65 + r];
    v.z = lds[(c4 * 4 + 2) * 65 + r];
    v.w = lds[(c4 * 4 + 3) * 65 + r];
    *(float4*)(out + (row0 + r) * (long)OUTSTRIDE + c4 * 4) = v;
  }
}

// ---------------- fused ResBlock PAIR, weights staged in LDS (proven R6) ----------------
__global__ __launch_bounds__(512, 4) void resblock_pair_k(
    float* xbuf, const float* __restrict__ waP, const float* __restrict__ ba,
    const float* __restrict__ wbT, const float* __restrict__ bb) {
  __shared__ float wls[8192];
  __shared__ float ts[64][36];
  const int tid = threadIdx.x, lane = tid & 63, wv = tid >> 6;
  const long row0 = (long)blockIdx.x * 64;
  const int o32 = lane & 31, rh = lane >> 5;

  for (int li = 0; li < 2; ++li) {
    __syncthreads();
    for (int i = tid; i < 8192; i += 512) wls[i] = waP[li * 8192 + i];
    __syncthreads();

    {
      float a0 = 0.f, a1 = 0.f, a2 = 0.f, a3 = 0.f;
      const float* xrow = xbuf + (row0 + wv * 8 + rh * 4) * (long)SB;
#pragma unroll 4
      for (int k0 = 0; k0 < 256; k0 += 4) {
        const float4 wq = *(const float4*)(&wls[k0 * 32 + o32 * 4]);
        const float4 x0 = *(const float4*)(xrow + 0 * SB + k0);
        const float4 x1 = *(const float4*)(xrow + 1 * SB + k0);
        const float4 x2 = *(const float4*)(xrow + 2 * SB + k0);
        const float4 x3 = *(const float4*)(xrow + 3 * SB + k0);
        a0 = fmaf(frelu(x0.x), wq.x, a0);
        a0 = fmaf(frelu(x0.y), wq.y, a0);
        a0 = fmaf(frelu(x0.z), wq.z, a0);
        a0 = fmaf(frelu(x0.w), wq.w, a0);
        a1 = fmaf(frelu(x1.x), wq.x, a1);
        a1 = fmaf(frelu(x1.y), wq.y, a1);
        a1 = fmaf(frelu(x1.z), wq.z, a1);
        a1 = fmaf(frelu(x1.w), wq.w, a1);
        a2 = fmaf(frelu(x2.x), wq.x, a2);
        a2 = fmaf(frelu(x2.y), wq.y, a2);
        a2 = fmaf(frelu(x2.z), wq.z, a2);
        a2 = fmaf(frelu(x2.w), wq.w, a2);
        a3 = fmaf(frelu(x3.x), wq.x, a3);
        a3 = fmaf(frelu(x3.y), wq.y, a3);
        a3 = fmaf(frelu(x3.z), wq.z, a3);
        a3 = fmaf(frelu(x3.w), wq.w, a3);
      }
      const float bal = ba[li * 32 + o32];
      const int rB = wv * 8 + rh * 4;
      ts[rB + 0][o32] = frelu(a0 + bal);
      ts[rB + 1][o32] = frelu(a1 + bal);
      ts[rB + 2][o32] = frelu(a2 + bal);
      ts[rB + 3][o32] = frelu(a3 + bal);
    }

    __syncthreads();
    for (int i = tid; i < 8192; i += 512) wls[i] = wbT[li * 8192 + i];
    __syncthreads();

    float acc2[8][4];
#pragma unroll
    for (int i = 0; i < 8; ++i)
#pragma unroll
      for (int j = 0; j < 4; ++j) acc2[i][j] = 0.f;

#pragma unroll
    for (int k0 = 0; k0 < 32; k0 += 4) {
      const float4 wk0 = *(const float4*)(&wls[(k0 + 0) * 256 + lane * 4]);
      const float4 wk1 = *(const float4*)(&wls[(k0 + 1) * 256 + lane * 4]);
      const float4 wk2 = *(const float4*)(&wls[(k0 + 2) * 256 + lane * 4]);
      const float4 wk3 = *(const float4*)(&wls[(k0 + 3) * 256 + lane * 4]);
#pragma unroll
      for (int rj = 0; rj < 8; ++rj) {
        const float4 t4 = *(const float4*)(&ts[wv * 8 + rj][k0]);
        acc2[rj][0] = fmaf(t4.x, wk0.x, acc2[rj][0]);
        acc2[rj][1] = fmaf(t4.x, wk0.y, acc2[rj][1]);
        acc2[rj][2] = fmaf(t4.x, wk0.z, acc2[rj][2]);
        acc2[rj][3] = fmaf(t4.x, wk0.w, acc2[rj][3]);
        acc2[rj][0] = fmaf(t4.y, wk1.x, acc2[rj][0]);
        acc2[rj][1] = fmaf(t4.y, wk1.y, acc2[rj][1]);
        acc2[rj][2] = fmaf(t4.y, wk1.z, acc2[rj][2]);
        acc2[rj][3] = fmaf(t4.y, wk1.w, acc2[rj][3]);
        acc2[rj][0] = fmaf(t4.z, wk2.x, acc2[rj][0]);
        acc2[rj][1] = fmaf(t4.z, wk2.y, acc2[rj][1]);
        acc2[rj][2] = fmaf(t4.z, wk2.z, acc2[rj][2]);
        acc2[rj][3] = fmaf(t4.z, wk2.w, acc2[rj][3]);
        acc2[rj][0] = fmaf(t4.w, wk3.x, acc2[rj][0]);
        acc2[rj][1] = fmaf(t4.w, wk3.y, acc2[rj][1]);
        acc2[rj][2] = fmaf(t4.w, wk3.z, acc2[rj][2]);
        acc2[rj][3] = fmaf(t4.w, wk3.w, acc2[rj][3]);
      }
    }
    const float4 bbv = *(const float4*)(bb + li * 256 + lane * 4);
#pragma unroll
    for (int rj = 0; rj < 8; ++rj) {
      float* xp = xbuf + (row0 + wv * 8 + rj) * (long)SB + lane * 4;
      const float4 xv = *(const float4*)xp;
      float4 nv;
      nv.x = xv.x + acc2[rj][0] + bbv.x;
      nv.y = xv.y + acc2[rj][1] + bbv.y;
      nv.z = xv.z + acc2[rj][2] + bbv.z;
      nv.w = xv.w + acc2[rj][3] + bbv.w;
      *(float4*)xp = nv;
    }
  }
}

// ---------------- vq8_k: q-conv + VQ with SCALAR codebook + dec1 ------------------
// R13 analysis: per-lane codebook vector loads saturate TA/L1 at 1.0 (16 lines per
// e-load inst) -> VALU capped ~62%. Fix: lane = ROW. Each lane holds its row's
// residual in 64 VGPRs; codes are a UNIFORM loop -> etg[k][d] and en2[k] are
// wave-uniform -> s_load (scalar pipe); dot = 64 v_fma with SGPR operand.
// Inner loop uses ZERO TA lines and ZERO LDS. 2 codes in flight = dep-chain ILP.
// Wave w scans ascending code range [w*128,(w+1)*128); per-code chain is
// d-ascending (bit-identical scores to R13); cross-wave argmin combine in wave
// order keeps exact first-min tie-break. 64 rows/block, 4 waves, grid 1024.
__global__ __launch_bounds__(256, 2) void vq8_k(
    float* buf, const float* __restrict__ wTq, const float* __restrict__ qb,
    const float* __restrict__ en2, const float* __restrict__ etg,
    float* __restrict__ dsum, const float* __restrict__ wTd1, const float* __restrict__ d1b) {
  __shared__ float q_lds[64 * 72];   // quant staging / per-level gathered q (pad 72: 4-way max)
  __shared__ float mq_lds[64 * 72];  // main_q for dec1
  __shared__ float bestvL[256];
  __shared__ int bestkL[256];
  __shared__ int kwin[64];
  const int tid = threadIdx.x, lane = tid & 63, wv = tid >> 6;
  const long row0 = (long)blockIdx.x * 64;

  // ---- phase A: q-conv (wave w: rows w*16..+15, lane = output) ----
  {
    float acc[16];
#pragma unroll
    for (int i = 0; i < 16; ++i) acc[i] = 0.f;
    const float* xbase = buf + (row0 + wv * 16) * (long)SB;
#pragma unroll 2
    for (int k0 = 0; k0 < 256; k0 += 4) {
      const float w0 = wTq[(k0 + 0) * 64 + lane];
      const float w1 = wTq[(k0 + 1) * 64 + lane];
      const float w2 = wTq[(k0 + 2) * 64 + lane];
      const float w3 = wTq[(k0 + 3) * 64 + lane];
#pragma unroll
      for (int rj = 0; rj < 16; ++rj) {
        const float4 x = *(const float4*)(xbase + (long)rj * SB + k0);
        acc[rj] = fmaf(frelu(x.x), w0, acc[rj]);
        acc[rj] = fmaf(frelu(x.y), w1, acc[rj]);
        acc[rj] = fmaf(frelu(x.z), w2, acc[rj]);
        acc[rj] = fmaf(frelu(x.w), w3, acc[rj]);
      }
    }
    const float qbv = qb[lane];
#pragma unroll
    for (int rj = 0; rj < 16; ++rj) q_lds[(wv * 16 + rj) * 72 + lane] = acc[rj] + qbv;
  }
  __syncthreads();

  // ---- load residual: lane = row, 64 dims in registers ----
  float res[64];
#pragma unroll
  for (int c = 0; c < 16; ++c) {
    const float4 v = *(const float4*)(&q_lds[lane * 72 + c * 4]);
    res[c * 4 + 0] = v.x;
    res[c * 4 + 1] = v.y;
    res[c * 4 + 2] = v.z;
    res[c * 4 + 3] = v.w;
  }

  float dloc = 0.f;

  for (int l = 0; l < 4; ++l) {
    // ---- scan my 128 codes (2 at a time; per-code single d-ascending chain) ----
    float best = 3.4e38f;
    int bk = 0;
    const int kbase = wv * 128;
    const float* eb = etg + ((long)(l * 512 + kbase)) * 64;
    const float* e2p = en2 + l * 512 + kbase;
    for (int kk = 0; kk < 128; kk += 2) {
      const float* e1 = eb + (long)kk * 64;
      const float* e2 = e1 + 64;
      float a1 = 0.f, a2 = 0.f;
#pragma unroll
      for (int d = 0; d < 64; ++d) {
        a1 = fmaf(res[d], e1[d], a1);
        a2 = fmaf(res[d], e2[d], a2);
      }
      const float s1 = fmaf(-2.f, a1, e2p[kk]);
      const float s2 = fmaf(-2.f, a2, e2p[kk + 1]);
      if (s1 < best) { best = s1; bk = kbase + kk; }
      if (s2 < best) { best = s2; bk = kbase + kk + 1; }
    }
    bestvL[wv * 64 + lane] = best;
    bestkL[wv * 64 + lane] = bk;
    __syncthreads();

    // ---- cross-wave combine (wave ranges ascending in k; strict < = first-min) ----
    float bv = bestvL[lane];
    int bi = bestkL[lane];
#pragma unroll
    for (int w2 = 1; w2 < 4; ++w2) {
      const float ov = bestvL[w2 * 64 + lane];
      const int ok = bestkL[w2 * 64 + lane];
      if (ov < bv) { bv = ov; bi = ok; }
    }
    if (wv == 0) kwin[lane] = bi;
    __syncthreads();

    // ---- cooperative gather of winning codebook rows into q_lds ----
    {
      const int r = tid >> 2, part = tid & 3;
      const int kw = kwin[r];
      const float* src = etg + ((long)(l * 512 + kw)) * 64 + part * 16;
      const float4 f0 = *(const float4*)(src + 0);
      const float4 f1 = *(const float4*)(src + 4);
      const float4 f2 = *(const float4*)(src + 8);
      const float4 f3 = *(const float4*)(src + 12);
      float* dst = &q_lds[r * 72 + part * 16];
      *(float4*)(dst + 0) = f0;
      *(float4*)(dst + 4) = f1;
      *(float4*)(dst + 8) = f2;
      *(float4*)(dst + 12) = f3;
    }
    __syncthreads();

    // ---- straight-through update (exact reference sequence) ----
#pragma unroll
    for (int c = 0; c < 16; ++c) {
      const float4 q4 = *(const float4*)(&q_lds[lane * 72 + c * 4]);
      const float t0 = q4.x - res[c * 4 + 0];
      const float t1 = q4.y - res[c * 4 + 1];
      const float t2 = q4.z - res[c * 4 + 2];
      const float t3 = q4.w - res[c * 4 + 3];
      const float q0 = res[c * 4 + 0] + t0;
      const float q1 = res[c * 4 + 1] + t1;
      const float q2 = res[c * 4 + 2] + t2;
      const float q3 = res[c * 4 + 3] + t3;
      dloc = fmaf(t0, t0, dloc);
      dloc = fmaf(t1, t1, dloc);
      dloc = fmaf(t2, t2, dloc);
      dloc = fmaf(t3, t3, dloc);
      res[c * 4 + 0] -= q0;
      res[c * 4 + 1] -= q1;
      res[c * 4 + 2] -= q2;
      res[c * 4 + 3] -= q3;
      if (l == 0 && wv == 0) {
        float4 m;
        m.x = q0;
        m.y = q1;
        m.z = q2;
        m.w = q3;
        *(float4*)(&mq_lds[lane * 72 + c * 4]) = m;
      }
    }
  }

  // diff accumulation: all waves computed identical dloc; wave 0 commits
  if (wv == 0) {
#pragma unroll
    for (int m = 1; m < 64; m <<= 1) dloc += __shfl_xor(dloc, m, 64);
    if (lane == 0) atomicAdd(dsum, dloc);
  }
  __syncthreads();  // mq_lds visible to all waves for dec1

  // ---- phase C: dec1 (wave w: rows w*16..+15, lane owns 4 outputs) ----
  {
    float acc1[16][4];
#pragma unroll
    for (int i = 0; i < 16; ++i)
#pragma unroll
      for (int j = 0; j < 4; ++j) acc1[i][j] = 0.f;

    const float* w1b = wTd1 + lane * 4;
#pragma unroll 2
    for (int d0 = 0; d0 < 64; d0 += 4) {
      const float4 wA = *(const float4*)(w1b + (d0 + 0) * 256);
      const float4 wB = *(const float4*)(w1b + (d0 + 1) * 256);
      const float4 wC = *(const float4*)(w1b + (d0 + 2) * 256);
      const float4 wD = *(const float4*)(w1b + (d0 + 3) * 256);
#pragma unroll
      for (int rj = 0; rj < 16; ++rj) {
        const float4 x = *(const float4*)(&mq_lds[(wv * 16 + rj) * 72 + d0]);
        acc1[rj][0] = fmaf(x.x, wA.x, acc1[rj][0]);
        acc1[rj][1] = fmaf(x.x, wA.y, acc1[rj][1]);
        acc1[rj][2] = fmaf(x.x, wA.z, acc1[rj][2]);
        acc1[rj][3] = fmaf(x.x, wA.w, acc1[rj][3]);
        acc1[rj][0] = fmaf(x.y, wB.x, acc1[rj][0]);
        acc1[rj][1] = fmaf(x.y, wB.y, acc1[rj][1]);
        acc1[rj][2] = fmaf(x.y, wB.z, acc1[rj][2]);
        acc1[rj][3] = fmaf(x.y, wB.w, acc1[rj][3]);
        acc1[rj][0] = fmaf(x.z, wC.x, acc1[rj][0]);
        acc1[rj][1] = fmaf(x.z, wC.y, acc1[rj][1]);
        acc1[rj][2] = fmaf(x.z, wC.z, acc1[rj][2]);
        acc1[rj][3] = fmaf(x.z, wC.w, acc1[rj][3]);
        acc1[rj][0] = fmaf(x.w, wD.x, acc1[rj][0]);
        acc1[rj][1] = fmaf(x.w, wD.y, acc1[rj][1]);
        acc1[rj][2] = fmaf(x.w, wD.z, acc1[rj][2]);
        acc1[rj][3] = fmaf(x.w, wD.w, acc1[rj][3]);
      }
    }
    const float4 bv4 = *(const float4*)(d1b + lane * 4);
#pragma unroll
    for (int rj = 0; rj < 16; ++rj) {
      float4 v;
      v.x = acc1[rj][0] + bv4.x;
      v.y = acc1[rj][1] + bv4.y;
      v.z = acc1[rj][2] + bv4.z;
      v.w = acc1[rj][3] + bv4.w;
      *(float4*)(buf + (row0 + wv * 16 + rj) * (long)SB + lane * 4) = v;
    }
  }
}

// ---------------- FUSED decoder tail: d2 (256->128, relu both) + d3 (128->165) --------
__global__ __launch_bounds__(256, 3) void dec23_k(const float* __restrict__ in,
                                                  const float* __restrict__ wTd2,
                                                  const float* __restrict__ b2,
                                                  const float* __restrict__ wTd3,
                                                  const float* __restrict__ b3,
                                                  float* __restrict__ out) {
  __shared__ float xs[32][256];
  __shared__ float ts[32][132];
  const int tid = threadIdx.x, lane = tid & 63, wv = tid >> 6;
  const long row0 = (long)blockIdx.x * 32;

  for (int i = tid; i < 32 * 256; i += 256) {
    const int r = i >> 8, c = i & 255;
    xs[r][c] = frelu(in[(row0 + r) * (long)SB + c]);
  }
  __syncthreads();

  {
    float a2[8][2];
#pragma unroll
    for (int i = 0; i < 8; ++i) {
      a2[i][0] = 0.f;
      a2[i][1] = 0.f;
    }
    const float* w2base = wTd2 + lane * 2;
#pragma unroll 2
    for (int k0 = 0; k0 < 256; k0 += 4) {
      const float2 w0 = *(const float2*)(w2base + (k0 + 0) * 128);
      const float2 w1 = *(const float2*)(w2base + (k0 + 1) * 128);
      const float2 w2v = *(const float2*)(w2base + (k0 + 2) * 128);
      const float2 w3 = *(const float2*)(w2base + (k0 + 3) * 128);
#pragma unroll
      for (int rj = 0; rj < 8; ++rj) {
        const float4 x = *(const float4*)(&xs[wv * 8 + rj][k0]);
        a2[rj][0] = fmaf(x.x, w0.x, a2[rj][0]);
        a2[rj][1] = fmaf(x.x, w0.y, a2[rj][1]);
        a2[rj][0] = fmaf(x.y, w1.x, a2[rj][0]);
        a2[rj][1] = fmaf(x.y, w1.y, a2[rj][1]);
        a2[rj][0] = fmaf(x.z, w2v.x, a2[rj][0]);
        a2[rj][1] = fmaf(x.z, w2v.y, a2[rj][1]);
        a2[rj][0] = fmaf(x.w, w3.x, a2[rj][0]);
        a2[rj][1] = fmaf(x.w, w3.y, a2[rj][1]);
      }
    }
    const float b20 = b2[lane * 2 + 0];
    const float b21 = b2[lane * 2 + 1];
#pragma unroll
    for (int rj = 0; rj < 8; ++rj) {
      const int r = wv * 8 + rj;
      ts[r][lane * 2 + 0] = frelu(a2[rj][0] + b20);
      ts[r][lane * 2 + 1] = frelu(a2[rj][1] + b21);
    }
  }
  // ts rows are wave-private: no barrier needed

  {
    float a3[8][4];
#pragma unroll
    for (int i = 0; i < 8; ++i)
#pragma unroll
      for (int j = 0; j < 4; ++j) a3[i][j] = 0.f;

    const float* w3base = wTd3 + lane * 4;
#pragma unroll 2
    for (int k0 = 0; k0 < 128; k0 += 4) {
      const float4 wk0 = *(const float4*)(w3base + (k0 + 0) * 256);
      const float4 wk1 = *(const float4*)(w3base + (k0 + 1) * 256);
      const float4 wk2 = *(const float4*)(w3base + (k0 + 2) * 256);
      const float4 wk3 = *(const float4*)(w3base + (k0 + 3) * 256);
#pragma unroll
      for (int rj = 0; rj < 8; ++rj) {
        const float4 t4 = *(const float4*)(&ts[wv * 8 + rj][k0]);
        a3[rj][0] = fmaf(t4.x, wk0.x, a3[rj][0]);
        a3[rj][1] = fmaf(t4.x, wk0.y, a3[rj][1]);
        a3[rj][2] = fmaf(t4.x, wk0.z, a3[rj][2]);
        a3[rj][3] = fmaf(t4.x, wk0.w, a3[rj][3]);
        a3[rj][0] = fmaf(t4.y, wk1.x, a3[rj][0]);
        a3[rj][1] = fmaf(t4.y, wk1.y, a3[rj][1]);
        a3[rj][2] = fmaf(t4.y, wk1.z, a3[rj][2]);
        a3[rj][3] = fmaf(t4.y, wk1.w, a3[rj][3]);
        a3[rj][0] = fmaf(t4.z, wk2.x, a3[rj][0]);
        a3[rj][1] = fmaf(t4.z, wk2.y, a3[rj][1]);
        a3[rj][2] = fmaf(t4.z, wk2.z, a3[rj][2]);
        a3[rj][3] = fmaf(t4.z, wk2.w, a3[rj][3]);
        a3[rj][0] = fmaf(t4.w, wk3.x, a3[rj][0]);
        a3[rj][1] = fmaf(t4.w, wk3.y, a3[rj][1]);
        a3[rj][2] = fmaf(t4.w, wk3.z, a3[rj][2]);
        a3[rj][3] = fmaf(t4.w, wk3.w, a3[rj][3]);
      }
    }
    float bias[4];
#pragma unroll
    for (int j = 0; j < 4; ++j) {
      const int o = lane * 4 + j;
      bias[j] = (o < 165) ? b3[o] : 0.f;
    }
#pragma unroll
    for (int rj = 0; rj < 8; ++rj) {
      const long rbase = (row0 + wv * 8 + rj) * 165L;
#pragma unroll
      for (int j = 0; j < 4; ++j) {
        const int o = lane * 4 + j;
        if (o < 165) out[rbase + o] = a3[rj][j] + bias[j];
      }
    }
  }
}

__global__ void finalize_k(const float* __restrict__ dsum, float* __restrict__ out) {
  if (threadIdx.x == 0 && blockIdx.x == 0)
    out[0] = *dsum * (1.0f / (4.0f * 65536.0f * 64.0f));
}

// ---------------- launch ----------------
extern "C" void kernel_launch(void* const* d_in, const int* in_sizes, int n_in, void* d_out,
                              int out_size, void* d_ws, size_t ws_size, hipStream_t stream) {
  (void)in_sizes; (void)n_in; (void)out_size; (void)ws_size;
  const float* x = (const float*)d_in[0];
  const float* enc_w1 = (const float*)d_in[1];
  const float* enc_b1 = (const float*)d_in[2];
  const float* enc_w2 = (const float*)d_in[3];
  const float* enc_b2 = (const float*)d_in[4];
  const float* enc_w3 = (const float*)d_in[5];
  const float* enc_b3 = (const float*)d_in[6];
  const float* enc_res_wa = (const float*)d_in[7];
  const float* enc_res_ba = (const float*)d_in[8];
  const float* enc_res_wb = (const float*)d_in[9];
  const float* enc_res_bb = (const float*)d_in[10];
  const float* q_w = (const float*)d_in[11];
  const float* q_b = (const float*)d_in[12];
  const float* embeds = (const float*)d_in[13];
  const float* dec_w1 = (const float*)d_in[14];
  const float* dec_b1 = (const float*)d_in[15];
  const float* dec_res_wa = (const float*)d_in[16];
  const float* dec_res_ba = (const float*)d_in[17];
  const float* dec_res_wb = (const float*)d_in[18];
  const float* dec_res_bb = (const float*)d_in[19];
  const float* dec_w2 = (const float*)d_in[20];
  const float* dec_b2 = (const float*)d_in[21];
  const float* dec_w3 = (const float*)d_in[22];
  const float* dec_b3 = (const float*)d_in[23];

  float* ws = (float*)d_ws;
  float* buf = ws;                          // [N][256]
  float* W = ws + (long)NROWS * SB;         // weight/codebook region

  float* dout = (float*)d_out;

  prep_k<<<(PREP_N + 255) / 256, 256, 0, stream>>>(enc_w1, enc_w2, enc_w3, q_w, dec_w1, dec_w2,
                                                   dec_w3, enc_res_wa, enc_res_wb, dec_res_wa,
                                                   dec_res_wb, embeds, W);

  const int GB = NROWS / 32;   // 2048 blocks (conv2, dec23)
  const int GR = NROWS / 64;   // 1024 blocks (conv6, resblock pairs, vq8)

  // encoder
  conv2_k<165, 168, 128, 2, 165, SB, false, true><<<GB, 256, 0, stream>>>(x, W + OFF_WT1, enc_b1, buf);
  conv6_k<128, 256, 256, SB, SB, false, true><<<GR, 512, 0, stream>>>(buf, W + OFF_WT2, enc_b2, buf);
  conv6_k<256, 256, 256, SB, SB, false, false><<<GR, 512, 0, stream>>>(buf, W + OFF_WT3, enc_b3, buf);
  resblock_pair_k<<<GR, 512, 0, stream>>>(buf, W + OFF_WAPE, enc_res_ba, W + OFF_WBTE, enc_res_bb);

  // q-conv + residual VQ + dec1 (fused, scalar-codebook)
  vq8_k<<<GR, 256, 0, stream>>>(buf, W + OFF_WTQ, q_b, W + OFF_EN2, W + OFF_ETG, W + OFF_DSUM,
                                W + OFF_WTD1, dec_b1);

  // decoder
  resblock_pair_k<<<GR, 512, 0, stream>>>(buf, W + OFF_WAPD, dec_res_ba, W + OFF_WBTD, dec_res_bb);
  dec23_k<<<GB, 256, 0, stream>>>(buf, W + OFF_WTD2, dec_b2, W + OFF_WTD3, dec_b3, dout);

  finalize_k<<<1, 64, 0, stream>>>(W + OFF_DSUM, dout + (long)NROWS * 165);
}

// Round 15
// 1156.545 us; speedup vs baseline: 1.6348x; 1.6348x over previous
//
#include <hip/hip_runtime.h>

#define NROWS 65536
#define SB 256  // stride of the main ws activation buffer

__device__ __forceinline__ float frelu(float v) { return fmaxf(v, 0.f); }

// ---------------- ws layout (floats, relative to weight region W) ----------------
#define OFF_WT1   0        // [168][128]  enc_w1^T
#define OFF_WT2   21504    // [128][256]  enc_w2^T
#define OFF_WT3   54272    // [256][256]  enc_w3^T
#define OFF_WTQ   119808   // [256][64]   q_w^T
#define OFF_WTD1  136192   // [64][256]   dec_w1^T
#define OFF_WTD2  152576   // [256][128]  dec_w2^T
#define OFF_WTD3  185344   // [128][256]  dec_w3^T (o>=165 zero-padded)
#define OFF_WAPE  218112   // [2][64][32][4] enc_res_wa packed
#define OFF_WBTE  234496   // [2][32][256]   enc_res_wb^T
#define OFF_WAPD  250880   // [2][64][32][4] dec_res_wa packed
#define OFF_WBTD  267264   // [2][32][256]   dec_res_wb^T
#define OFF_ETG   283648   // [4][512][64]  codebook row-major
#define OFF_EN2   414720   // [4][512]      ||e_k||^2
#define OFF_DSUM  416768   // [1]
#define PREP_N    416769

// ---------------- fused prep kernel ----------------
__global__ void prep_k(const float* __restrict__ ew1, const float* __restrict__ ew2,
                       const float* __restrict__ ew3, const float* __restrict__ qw,
                       const float* __restrict__ dw1, const float* __restrict__ dw2,
                       const float* __restrict__ dw3, const float* __restrict__ ewa,
                       const float* __restrict__ ewb, const float* __restrict__ dwa,
                       const float* __restrict__ dwb, const float* __restrict__ embeds,
                       float* __restrict__ W) {
  int idx = blockIdx.x * 256 + threadIdx.x;
  if (idx < 21504) {  // wT1 [168][128] <- ew1 [128][165]
    int k = idx >> 7, o = idx & 127;
    W[OFF_WT1 + idx] = (k < 165) ? ew1[o * 165 + k] : 0.f;
    return;
  }
  idx -= 21504;
  if (idx < 32768) {  // wT2 [128][256]
    int k = idx >> 8, o = idx & 255;
    W[OFF_WT2 + idx] = ew2[o * 128 + k];
    return;
  }
  idx -= 32768;
  if (idx < 65536) {  // wT3 [256][256]
    int k = idx >> 8, o = idx & 255;
    W[OFF_WT3 + idx] = ew3[o * 256 + k];
    return;
  }
  idx -= 65536;
  if (idx < 16384) {  // wTq [256][64]
    int k = idx >> 6, o = idx & 63;
    W[OFF_WTQ + idx] = qw[o * 256 + k];
    return;
  }
  idx -= 16384;
  if (idx < 16384) {  // wTd1 [64][256]
    int k = idx >> 8, o = idx & 255;
    W[OFF_WTD1 + idx] = dw1[o * 64 + k];
    return;
  }
  idx -= 16384;
  if (idx < 32768) {  // wTd2 [256][128]
    int k = idx >> 7, o = idx & 127;
    W[OFF_WTD2 + idx] = dw2[o * 256 + k];
    return;
  }
  idx -= 32768;
  if (idx < 32768) {  // wTd3 [128][256], pad o>=165
    int k = idx >> 8, o = idx & 255;
    W[OFF_WTD3 + idx] = (o < 165) ? dw3[o * 128 + k] : 0.f;
    return;
  }
  idx -= 32768;
  if (idx < 16384) {  // waPe
    int l = idx >> 13, rem = idx & 8191;
    int k4 = rem >> 7, rem2 = rem & 127, o = rem2 >> 2, kk = rem2 & 3;
    W[OFF_WAPE + idx] = ewa[l * 8192 + o * 256 + k4 * 4 + kk];
    return;
  }
  idx -= 16384;
  if (idx < 16384) {  // wbTe
    int l = idx >> 13, rem = idx & 8191;
    int k = rem >> 8, o = rem & 255;
    W[OFF_WBTE + idx] = ewb[l * 8192 + o * 32 + k];
    return;
  }
  idx -= 16384;
  if (idx < 16384) {  // waPd
    int l = idx >> 13, rem = idx & 8191;
    int k4 = rem >> 7, rem2 = rem & 127, o = rem2 >> 2, kk = rem2 & 3;
    W[OFF_WAPD + idx] = dwa[l * 8192 + o * 256 + k4 * 4 + kk];
    return;
  }
  idx -= 16384;
  if (idx < 16384) {  // wbTd
    int l = idx >> 13, rem = idx & 8191;
    int k = rem >> 8, o = rem & 255;
    W[OFF_WBTD + idx] = dwb[l * 8192 + o * 32 + k];
    return;
  }
  idx -= 16384;
  if (idx < 131072) {  // etg[l][k][d]
    int d = idx & 63, k = (idx >> 6) & 511, l = idx >> 15;
    W[OFF_ETG + idx] = embeds[(l * 64 + d) * 512 + k];
    return;
  }
  idx -= 131072;
  if (idx < 2048) {  // en2
    int l = idx >> 9, k = idx & 511;
    float s = 0.f;
    for (int d = 0; d < 64; ++d) {
      float e = embeds[(l * 64 + d) * 512 + k];
      s = fmaf(e, e, s);
    }
    W[OFF_EN2 + idx] = s;
    return;
  }
  idx -= 2048;
  if (idx == 0) W[OFF_DSUM] = 0.f;
}

// ---------------- conv2_k: R6 proven form (LDS x-stage, lane=output) ----------------
template <int CIN, int CINP, int COUT, int CP, int INSTRIDE, int OUTSTRIDE, bool RELU_IN,
          bool RELU_OUT>
__global__ __launch_bounds__(256, 4) void conv2_k(const float* in, const float* __restrict__ wT,
                                                  const float* __restrict__ b, float* out) {
  constexpr int COUTP = 64 * CP;
  constexpr bool GUARD = (COUT != COUTP);
  typedef float vCP __attribute__((ext_vector_type(CP)));
  __shared__ float xs[32][CINP];
  const int tid = threadIdx.x, lane = tid & 63, wv = tid >> 6;
  const long row0 = (long)blockIdx.x * 32;

  for (int i = tid; i < 32 * CINP; i += 256) {
    const int r = i / CINP, c = i % CINP;
    float v = (CIN == CINP || c < CIN) ? in[(row0 + r) * (long)INSTRIDE + c] : 0.f;
    if (RELU_IN) v = frelu(v);
    xs[r][c] = v;
  }
  __syncthreads();

  float acc[8][CP];
#pragma unroll
  for (int i = 0; i < 8; ++i)
#pragma unroll
    for (int j = 0; j < CP; ++j) acc[i][j] = 0.f;

  const float* wbase = wT + lane * CP;
#pragma unroll 4
  for (int k0 = 0; k0 < CINP; k0 += 4) {
    vCP wk[4];
#pragma unroll
    for (int kk = 0; kk < 4; ++kk) wk[kk] = *(const vCP*)(wbase + (k0 + kk) * COUTP);
#pragma unroll
    for (int rj = 0; rj < 8; ++rj) {
      const float4 x = *(const float4*)(&xs[wv * 8 + rj][k0]);
#pragma unroll
      for (int j = 0; j < CP; ++j) {
        acc[rj][j] = fmaf(x.x, wk[0][j], acc[rj][j]);
        acc[rj][j] = fmaf(x.y, wk[1][j], acc[rj][j]);
        acc[rj][j] = fmaf(x.z, wk[2][j], acc[rj][j]);
        acc[rj][j] = fmaf(x.w, wk[3][j], acc[rj][j]);
      }
    }
  }

  float bias[CP];
#pragma unroll
  for (int j = 0; j < CP; ++j) {
    const int o = lane * CP + j;
    bias[j] = (!GUARD || o < COUT) ? b[o] : 0.f;
  }
#pragma unroll
  for (int rj = 0; rj < 8; ++rj) {
    const long rbase = (row0 + wv * 8 + rj) * (long)OUTSTRIDE;
    if constexpr (!GUARD) {
      vCP v;
#pragma unroll
      for (int j = 0; j < CP; ++j) {
        const float t = acc[rj][j] + bias[j];
        v[j] = RELU_OUT ? frelu(t) : t;
      }
      *(vCP*)(out + rbase + lane * CP) = v;
    } else {
#pragma unroll
      for (int j = 0; j < CP; ++j) {
        const int o = lane * CP + j;
        if (o < COUT) {
          const float t = acc[rj][j] + bias[j];
          out[rbase + o] = RELU_OUT ? frelu(t) : t;
        }
      }
    }
  }
}

// ---------------- conv6_k: per-tile TRANSPOSED x (lane = row), scalar weights --------
template <int CIN, int COUT, int COUTP, int INSTRIDE, int OUTSTRIDE, bool RELU_IN, bool RELU_OUT>
__global__ __launch_bounds__(512, 2) void conv6_k(const float* __restrict__ in,
                                                  const float* __restrict__ wT,
                                                  const float* __restrict__ b,
                                                  float* __restrict__ out) {
  constexpr int MAXD = (CIN > COUT) ? CIN : COUT;
  __shared__ float lds[MAXD * 65];
  const int tid = threadIdx.x;
  const int lane = tid & 63;
  const int wv = __builtin_amdgcn_readfirstlane(tid >> 6);
  const long row0 = (long)blockIdx.x * 64;

  constexpr int C4 = CIN / 4;
  for (int i = tid; i < 64 * C4; i += 512) {
    const int r = i / C4, c4 = i % C4;
    float4 v = *(const float4*)(in + (row0 + r) * (long)INSTRIDE + c4 * 4);
    if (RELU_IN) {
      v.x = frelu(v.x);
      v.y = frelu(v.y);
      v.z = frelu(v.z);
      v.w = frelu(v.w);
    }
    lds[(c4 * 4 + 0) * 65 + r] = v.x;
    lds[(c4 * 4 + 1) * 65 + r] = v.y;
    lds[(c4 * 4 + 2) * 65 + r] = v.z;
    lds[(c4 * 4 + 3) * 65 + r] = v.w;
  }
  __syncthreads();

  float acc[32];
#pragma unroll
  for (int j = 0; j < 32; ++j) acc[j] = 0.f;

  const float* wrow = wT + wv * 32;
#pragma unroll 2
  for (int k = 0; k < CIN; ++k) {
    const float xv = lds[k * 65 + lane];
    const float* wk = wrow + (long)k * COUTP;
#pragma unroll
    for (int j = 0; j < 32; ++j) acc[j] = fmaf(xv, wk[j], acc[j]);
  }

  const float* bb = b + wv * 32;
#pragma unroll
  for (int j = 0; j < 32; ++j) {
    float t = acc[j] + bb[j];
    acc[j] = RELU_OUT ? frelu(t) : t;
  }

  __syncthreads();
#pragma unroll
  for (int j = 0; j < 32; ++j) lds[(wv * 32 + j) * 65 + lane] = acc[j];
  __syncthreads();

  constexpr int O4 = COUT / 4;
  for (int i = tid; i < 64 * O4; i += 512) {
    const int r = i / O4, c4 = i % O4;
    float4 v;
    v.x = lds[(c4 * 4 + 0) * 65 + r];
    v.y = lds[(c4 * 4 + 1) * 65 + r];
    v.z = lds[(c4 * 4 + 2) * 65 + r];
    v.w = lds[(c4 * 4 + 3) * 65 + r];
    *(float4*)(out + (row0 + r) * (long)OUTSTRIDE + c4 * 4) = v;
  }
}

// ---------------- fused ResBlock PAIR, weights staged in LDS (proven R6) ----------------
__global__ __launch_bounds__(512, 4) void resblock_pair_k(
    float* xbuf, const float* __restrict__ waP, const float* __restrict__ ba,
    const float* __restrict__ wbT, const float* __restrict__ bb) {
  __shared__ float wls[8192];
  __shared__ float ts[64][36];
  const int tid = threadIdx.x, lane = tid & 63, wv = tid >> 6;
  const long row0 = (long)blockIdx.x * 64;
  const int o32 = lane & 31, rh = lane >> 5;

  for (int li = 0; li < 2; ++li) {
    __syncthreads();
    for (int i = tid; i < 8192; i += 512) wls[i] = waP[li * 8192 + i];
    __syncthreads();

    {
      float a0 = 0.f, a1 = 0.f, a2 = 0.f, a3 = 0.f;
      const float* xrow = xbuf + (row0 + wv * 8 + rh * 4) * (long)SB;
#pragma unroll 4
      for (int k0 = 0; k0 < 256; k0 += 4) {
        const float4 wq = *(const float4*)(&wls[k0 * 32 + o32 * 4]);
        const float4 x0 = *(const float4*)(xrow + 0 * SB + k0);
        const float4 x1 = *(const float4*)(xrow + 1 * SB + k0);
        const float4 x2 = *(const float4*)(xrow + 2 * SB + k0);
        const float4 x3 = *(const float4*)(xrow + 3 * SB + k0);
        a0 = fmaf(frelu(x0.x), wq.x, a0);
        a0 = fmaf(frelu(x0.y), wq.y, a0);
        a0 = fmaf(frelu(x0.z), wq.z, a0);
        a0 = fmaf(frelu(x0.w), wq.w, a0);
        a1 = fmaf(frelu(x1.x), wq.x, a1);
        a1 = fmaf(frelu(x1.y), wq.y, a1);
        a1 = fmaf(frelu(x1.z), wq.z, a1);
        a1 = fmaf(frelu(x1.w), wq.w, a1);
        a2 = fmaf(frelu(x2.x), wq.x, a2);
        a2 = fmaf(frelu(x2.y), wq.y, a2);
        a2 = fmaf(frelu(x2.z), wq.z, a2);
        a2 = fmaf(frelu(x2.w), wq.w, a2);
        a3 = fmaf(frelu(x3.x), wq.x, a3);
        a3 = fmaf(frelu(x3.y), wq.y, a3);
        a3 = fmaf(frelu(x3.z), wq.z, a3);
        a3 = fmaf(frelu(x3.w), wq.w, a3);
      }
      const float bal = ba[li * 32 + o32];
      const int rB = wv * 8 + rh * 4;
      ts[rB + 0][o32] = frelu(a0 + bal);
      ts[rB + 1][o32] = frelu(a1 + bal);
      ts[rB + 2][o32] = frelu(a2 + bal);
      ts[rB + 3][o32] = frelu(a3 + bal);
    }

    __syncthreads();
    for (int i = tid; i < 8192; i += 512) wls[i] = wbT[li * 8192 + i];
    __syncthreads();

    float acc2[8][4];
#pragma unroll
    for (int i = 0; i < 8; ++i)
#pragma unroll
      for (int j = 0; j < 4; ++j) acc2[i][j] = 0.f;

#pragma unroll
    for (int k0 = 0; k0 < 32; k0 += 4) {
      const float4 wk0 = *(const float4*)(&wls[(k0 + 0) * 256 + lane * 4]);
      const float4 wk1 = *(const float4*)(&wls[(k0 + 1) * 256 + lane * 4]);
      const float4 wk2 = *(const float4*)(&wls[(k0 + 2) * 256 + lane * 4]);
      const float4 wk3 = *(const float4*)(&wls[(k0 + 3) * 256 + lane * 4]);
#pragma unroll
      for (int rj = 0; rj < 8; ++rj) {
        const float4 t4 = *(const float4*)(&ts[wv * 8 + rj][k0]);
        acc2[rj][0] = fmaf(t4.x, wk0.x, acc2[rj][0]);
        acc2[rj][1] = fmaf(t4.x, wk0.y, acc2[rj][1]);
        acc2[rj][2] = fmaf(t4.x, wk0.z, acc2[rj][2]);
        acc2[rj][3] = fmaf(t4.x, wk0.w, acc2[rj][3]);
        acc2[rj][0] = fmaf(t4.y, wk1.x, acc2[rj][0]);
        acc2[rj][1] = fmaf(t4.y, wk1.y, acc2[rj][1]);
        acc2[rj][2] = fmaf(t4.y, wk1.z, acc2[rj][2]);
        acc2[rj][3] = fmaf(t4.y, wk1.w, acc2[rj][3]);
        acc2[rj][0] = fmaf(t4.z, wk2.x, acc2[rj][0]);
        acc2[rj][1] = fmaf(t4.z, wk2.y, acc2[rj][1]);
        acc2[rj][2] = fmaf(t4.z, wk2.z, acc2[rj][2]);
        acc2[rj][3] = fmaf(t4.z, wk2.w, acc2[rj][3]);
        acc2[rj][0] = fmaf(t4.w, wk3.x, acc2[rj][0]);
        acc2[rj][1] = fmaf(t4.w, wk3.y, acc2[rj][1]);
        acc2[rj][2] = fmaf(t4.w, wk3.z, acc2[rj][2]);
        acc2[rj][3] = fmaf(t4.w, wk3.w, acc2[rj][3]);
      }
    }
    const float4 bbv = *(const float4*)(bb + li * 256 + lane * 4);
#pragma unroll
    for (int rj = 0; rj < 8; ++rj) {
      float* xp = xbuf + (row0 + wv * 8 + rj) * (long)SB + lane * 4;
      const float4 xv = *(const float4*)xp;
      float4 nv;
      nv.x = xv.x + acc2[rj][0] + bbv.x;
      nv.y = xv.y + acc2[rj][1] + bbv.y;
      nv.z = xv.z + acc2[rj][2] + bbv.z;
      nv.w = xv.w + acc2[rj][3] + bbv.w;
      *(float4*)xp = nv;
    }
  }
}

// ---------------- FUSED: q-conv + residual VQ (kc-fused 8 codes) + dec1 --------------
// R13 proven: 396us, VALU 62%, no spill. resL/mq alias into xs (dead after q-conv);
// kc-fused {8 rows, 8 codes/lane} VQ body; k-ascending first-min tie-break.
__global__ __launch_bounds__(256, 2) void vq_fused_k(
    float* buf, const float* __restrict__ wTq, const float* __restrict__ qb,
    const float* __restrict__ embeds, const float* __restrict__ en2,
    const float* __restrict__ etg, float* __restrict__ dsum,
    const float* __restrict__ wTd1, const float* __restrict__ d1b) {
  __shared__ float xs[32][256];  // [0..255]=relu(h); later [128..191]=resL, [192..255]=mq
  const int tid = threadIdx.x;
  const int lane = tid & 63;
  const int wv = tid >> 6;
  const long row0 = (long)blockIdx.x * 32;

  // ---- stage relu(h) ----
  for (int i = tid; i < 32 * 256; i += 256) {
    const int r = i >> 8, c = i & 255;
    xs[r][c] = frelu(buf[(row0 + r) * (long)SB + c]);
  }
  __syncthreads();

  // ---- q-conv head: resL[r][lane] = sum_k relu(h)[r][k] * wTq[k][lane] + qb ----
  {
    float qacc[8];
#pragma unroll
    for (int i = 0; i < 8; ++i) qacc[i] = 0.f;
#pragma unroll 2
    for (int k0 = 0; k0 < 256; k0 += 4) {
      const float w0 = wTq[(k0 + 0) * 64 + lane];
      const float w1 = wTq[(k0 + 1) * 64 + lane];
      const float w2 = wTq[(k0 + 2) * 64 + lane];
      const float w3 = wTq[(k0 + 3) * 64 + lane];
#pragma unroll
      for (int rj = 0; rj < 8; ++rj) {
        const float4 x = *(const float4*)(&xs[wv * 8 + rj][k0]);
        qacc[rj] = fmaf(x.x, w0, qacc[rj]);
        qacc[rj] = fmaf(x.y, w1, qacc[rj]);
        qacc[rj] = fmaf(x.z, w2, qacc[rj]);
        qacc[rj] = fmaf(x.w, w3, qacc[rj]);
      }
    }
    const float qbv = qb[lane];
#pragma unroll
    for (int rj = 0; rj < 8; ++rj) xs[wv * 8 + rj][128 + lane] = qacc[rj] + qbv;
  }

  // ---- residual VQ: kc-fused, 8 codes/lane ----
  float dloc = 0.f;

  for (int l = 0; l < 4; ++l) {
    float acc[8][8];
#pragma unroll
    for (int i = 0; i < 8; ++i)
#pragma unroll
      for (int j = 0; j < 8; ++j) acc[i][j] = 0.f;

    const float* eb0 = embeds + ((long)l << 15) + lane * 4;  // kc=0 chunk
    const float* eb1 = eb0 + 256;                            // kc=1 chunk

#pragma unroll 2
    for (int dq = 0; dq < 16; ++dq) {
      const float4 ea0 = *(const float4*)(eb0 + ((dq * 4 + 0) << 9));
      const float4 ea1 = *(const float4*)(eb0 + ((dq * 4 + 1) << 9));
      const float4 ea2 = *(const float4*)(eb0 + ((dq * 4 + 2) << 9));
      const float4 ea3 = *(const float4*)(eb0 + ((dq * 4 + 3) << 9));
      const float4 fb0 = *(const float4*)(eb1 + ((dq * 4 + 0) << 9));
      const float4 fb1 = *(const float4*)(eb1 + ((dq * 4 + 1) << 9));
      const float4 fb2 = *(const float4*)(eb1 + ((dq * 4 + 2) << 9));
      const float4 fb3 = *(const float4*)(eb1 + ((dq * 4 + 3) << 9));
#pragma unroll
      for (int rj = 0; rj < 8; ++rj) {
        const float4 x = *(const float4*)(&xs[wv * 8 + rj][128 + dq * 4]);
        acc[rj][0] = fmaf(x.x, ea0.x, acc[rj][0]);
        acc[rj][1] = fmaf(x.x, ea0.y, acc[rj][1]);
        acc[rj][2] = fmaf(x.x, ea0.z, acc[rj][2]);
        acc[rj][3] = fmaf(x.x, ea0.w, acc[rj][3]);
        acc[rj][4] = fmaf(x.x, fb0.x, acc[rj][4]);
        acc[rj][5] = fmaf(x.x, fb0.y, acc[rj][5]);
        acc[rj][6] = fmaf(x.x, fb0.z, acc[rj][6]);
        acc[rj][7] = fmaf(x.x, fb0.w, acc[rj][7]);
        acc[rj][0] = fmaf(x.y, ea1.x, acc[rj][0]);
        acc[rj][1] = fmaf(x.y, ea1.y, acc[rj][1]);
        acc[rj][2] = fmaf(x.y, ea1.z, acc[rj][2]);
        acc[rj][3] = fmaf(x.y, ea1.w, acc[rj][3]);
        acc[rj][4] = fmaf(x.y, fb1.x, acc[rj][4]);
        acc[rj][5] = fmaf(x.y, fb1.y, acc[rj][5]);
        acc[rj][6] = fmaf(x.y, fb1.z, acc[rj][6]);
        acc[rj][7] = fmaf(x.y, fb1.w, acc[rj][7]);
        acc[rj][0] = fmaf(x.z, ea2.x, acc[rj][0]);
        acc[rj][1] = fmaf(x.z, ea2.y, acc[rj][1]);
        acc[rj][2] = fmaf(x.z, ea2.z, acc[rj][2]);
        acc[rj][3] = fmaf(x.z, ea2.w, acc[rj][3]);
        acc[rj][4] = fmaf(x.z, fb2.x, acc[rj][4]);
        acc[rj][5] = fmaf(x.z, fb2.y, acc[rj][5]);
        acc[rj][6] = fmaf(x.z, fb2.z, acc[rj][6]);
        acc[rj][7] = fmaf(x.z, fb2.w, acc[rj][7]);
        acc[rj][0] = fmaf(x.w, ea3.x, acc[rj][0]);
        acc[rj][1] = fmaf(x.w, ea3.y, acc[rj][1]);
        acc[rj][2] = fmaf(x.w, ea3.z, acc[rj][2]);
        acc[rj][3] = fmaf(x.w, ea3.w, acc[rj][3]);
        acc[rj][4] = fmaf(x.w, fb3.x, acc[rj][4]);
        acc[rj][5] = fmaf(x.w, fb3.y, acc[rj][5]);
        acc[rj][6] = fmaf(x.w, fb3.z, acc[rj][6]);
        acc[rj][7] = fmaf(x.w, fb3.w, acc[rj][7]);
      }
    }

    // scores, k ascending (kc0 j0..3, then kc1 j0..3) — first-min tie-break preserved
    float best[8];
    int bk[8];
#pragma unroll
    for (int i = 0; i < 8; ++i) {
      best[i] = 3.4e38f;
      bk[i] = 0;
    }
    const float4 e2a = *(const float4*)(en2 + l * 512 + lane * 4);
    const float4 e2b = *(const float4*)(en2 + l * 512 + 256 + lane * 4);
#pragma unroll
    for (int rj = 0; rj < 8; ++rj) {
      float s;
      s = fmaf(-2.f, acc[rj][0], e2a.x);
      if (s < best[rj]) { best[rj] = s; bk[rj] = lane * 4 + 0; }
      s = fmaf(-2.f, acc[rj][1], e2a.y);
      if (s < best[rj]) { best[rj] = s; bk[rj] = lane * 4 + 1; }
      s = fmaf(-2.f, acc[rj][2], e2a.z);
      if (s < best[rj]) { best[rj] = s; bk[rj] = lane * 4 + 2; }
      s = fmaf(-2.f, acc[rj][3], e2a.w);
      if (s < best[rj]) { best[rj] = s; bk[rj] = lane * 4 + 3; }
      s = fmaf(-2.f, acc[rj][4], e2b.x);
      if (s < best[rj]) { best[rj] = s; bk[rj] = 256 + lane * 4 + 0; }
      s = fmaf(-2.f, acc[rj][5], e2b.y);
      if (s < best[rj]) { best[rj] = s; bk[rj] = 256 + lane * 4 + 1; }
      s = fmaf(-2.f, acc[rj][6], e2b.z);
      if (s < best[rj]) { best[rj] = s; bk[rj] = 256 + lane * 4 + 2; }
      s = fmaf(-2.f, acc[rj][7], e2b.w);
      if (s < best[rj]) { best[rj] = s; bk[rj] = 256 + lane * 4 + 3; }
    }

    // cross-lane first-min argmin
#pragma unroll
    for (int rj = 0; rj < 8; ++rj) {
      float bv = best[rj];
      int bi = bk[rj];
#pragma unroll
      for (int m = 1; m < 64; m <<= 1) {
        const float ov = __shfl_xor(bv, m, 64);
        const int ok = __shfl_xor(bi, m, 64);
        if (ov < bv || (ov == bv && ok < bi)) {
          bv = ov;
          bi = ok;
        }
      }
      bk[rj] = bi;
    }

    // gather + straight-through update (resL in xs[r][128+..], mq in xs[r][192+..])
#pragma unroll
    for (int rj = 0; rj < 8; ++rj) {
      const int r = wv * 8 + rj;
      const float q = etg[((long)((l << 9) + bk[rj])) * 64 + lane];
      const float res = xs[r][128 + lane];
      const float t = q - res;
      const float qst = res + t;
      dloc = fmaf(t, t, dloc);
      xs[r][128 + lane] = res - qst;
      if (l == 0) xs[r][192 + lane] = qst;
    }
  }

#pragma unroll
  for (int m = 1; m < 64; m <<= 1) dloc += __shfl_xor(dloc, m, 64);
  if (lane == 0) atomicAdd(dsum, dloc);

  // ---- dec1 tail: buf[r][o] = sum_d mq[r][d] * wTd1[d][o] + d1b[o] (no relu) ----
  {
    float acc1[8][4];
#pragma unroll
    for (int i = 0; i < 8; ++i)
#pragma unroll
      for (int j = 0; j < 4; ++j) acc1[i][j] = 0.f;

    const float* w1base = wTd1 + lane * 4;
#pragma unroll 2
    for (int d = 0; d < 64; d += 2) {
      const float4 wA = *(const float4*)(w1base + (d + 0) * 256);
      const float4 wB = *(const float4*)(w1base + (d + 1) * 256);
#pragma unroll
      for (int rj = 0; rj < 8; ++rj) {
        const int r = wv * 8 + rj;
        const float xA = xs[r][192 + d];
        const float xB = xs[r][192 + d + 1];
        acc1[rj][0] = fmaf(xA, wA.x, acc1[rj][0]);
        acc1[rj][1] = fmaf(xA, wA.y, acc1[rj][1]);
        acc1[rj][2] = fmaf(xA, wA.z, acc1[rj][2]);
        acc1[rj][3] = fmaf(xA, wA.w, acc1[rj][3]);
        acc1[rj][0] = fmaf(xB, wB.x, acc1[rj][0]);
        acc1[rj][1] = fmaf(xB, wB.y, acc1[rj][1]);
        acc1[rj][2] = fmaf(xB, wB.z, acc1[rj][2]);
        acc1[rj][3] = fmaf(xB, wB.w, acc1[rj][3]);
      }
    }
    const float4 bv = *(const float4*)(d1b + lane * 4);
#pragma unroll
    for (int rj = 0; rj < 8; ++rj) {
      float4 v;
      v.x = acc1[rj][0] + bv.x;
      v.y = acc1[rj][1] + bv.y;
      v.z = acc1[rj][2] + bv.z;
      v.w = acc1[rj][3] + bv.w;
      *(float4*)(buf + (row0 + wv * 8 + rj) * (long)SB + lane * 4) = v;
    }
  }
}

// ---------------- FUSED decoder tail: d2 (256->128, relu both) + d3 (128->165) --------
__global__ __launch_bounds__(256, 3) void dec23_k(const float* __restrict__ in,
                                                  const float* __restrict__ wTd2,
                                                  const float* __restrict__ b2,
                                                  const float* __restrict__ wTd3,
                                                  const float* __restrict__ b3,
                                                  float* __restrict__ out) {
  __shared__ float xs[32][256];
  __shared__ float ts[32][132];
  const int tid = threadIdx.x, lane = tid & 63, wv = tid >> 6;
  const long row0 = (long)blockIdx.x * 32;

  for (int i = tid; i < 32 * 256; i += 256) {
    const int r = i >> 8, c = i & 255;
    xs[r][c] = frelu(in[(row0 + r) * (long)SB + c]);
  }
  __syncthreads();

  {
    float a2[8][2];
#pragma unroll
    for (int i = 0; i < 8; ++i) {
      a2[i][0] = 0.f;
      a2[i][1] = 0.f;
    }
    const float* w2base = wTd2 + lane * 2;
#pragma unroll 2
    for (int k0 = 0; k0 < 256; k0 += 4) {
      const float2 w0 = *(const float2*)(w2base + (k0 + 0) * 128);
      const float2 w1 = *(const float2*)(w2base + (k0 + 1) * 128);
      const float2 w2v = *(const float2*)(w2base + (k0 + 2) * 128);
      const float2 w3 = *(const float2*)(w2base + (k0 + 3) * 128);
#pragma unroll
      for (int rj = 0; rj < 8; ++rj) {
        const float4 x = *(const float4*)(&xs[wv * 8 + rj][k0]);
        a2[rj][0] = fmaf(x.x, w0.x, a2[rj][0]);
        a2[rj][1] = fmaf(x.x, w0.y, a2[rj][1]);
        a2[rj][0] = fmaf(x.y, w1.x, a2[rj][0]);
        a2[rj][1] = fmaf(x.y, w1.y, a2[rj][1]);
        a2[rj][0] = fmaf(x.z, w2v.x, a2[rj][0]);
        a2[rj][1] = fmaf(x.z, w2v.y, a2[rj][1]);
        a2[rj][0] = fmaf(x.w, w3.x, a2[rj][0]);
        a2[rj][1] = fmaf(x.w, w3.y, a2[rj][1]);
      }
    }
    const float b20 = b2[lane * 2 + 0];
    const float b21 = b2[lane * 2 + 1];
#pragma unroll
    for (int rj = 0; rj < 8; ++rj) {
      const int r = wv * 8 + rj;
      ts[r][lane * 2 + 0] = frelu(a2[rj][0] + b20);
      ts[r][lane * 2 + 1] = frelu(a2[rj][1] + b21);
    }
  }
  // ts rows are wave-private: no barrier needed

  {
    float a3[8][4];
#pragma unroll
    for (int i = 0; i < 8; ++i)
#pragma unroll
      for (int j = 0; j < 4; ++j) a3[i][j] = 0.f;

    const float* w3base = wTd3 + lane * 4;
#pragma unroll 2
    for (int k0 = 0; k0 < 128; k0 += 4) {
      const float4 wk0 = *(const float4*)(w3base + (k0 + 0) * 256);
      const float4 wk1 = *(const float4*)(w3base + (k0 + 1) * 256);
      const float4 wk2 = *(const float4*)(w3base + (k0 + 2) * 256);
      const float4 wk3 = *(const float4*)(w3base + (k0 + 3) * 256);
#pragma unroll
      for (int rj = 0; rj < 8; ++rj) {
        const float4 t4 = *(const float4*)(&ts[wv * 8 + rj][k0]);
        a3[rj][0] = fmaf(t4.x, wk0.x, a3[rj][0]);
        a3[rj][1] = fmaf(t4.x, wk0.y, a3[rj][1]);
        a3[rj][2] = fmaf(t4.x, wk0.z, a3[rj][2]);
        a3[rj][3] = fmaf(t4.x, wk0.w, a3[rj][3]);
        a3[rj][0] = fmaf(t4.y, wk1.x, a3[rj][0]);
        a3[rj][1] = fmaf(t4.y, wk1.y, a3[rj][1]);
        a3[rj][2] = fmaf(t4.y, wk1.z, a3[rj][2]);
        a3[rj][3] = fmaf(t4.y, wk1.w, a3[rj][3]);
        a3[rj][0] = fmaf(t4.z, wk2.x, a3[rj][0]);
        a3[rj][1] = fmaf(t4.z, wk2.y, a3[rj][1]);
        a3[rj][2] = fmaf(t4.z, wk2.z, a3[rj][2]);
        a3[rj][3] = fmaf(t4.z, wk2.w, a3[rj][3]);
        a3[rj][0] = fmaf(t4.w, wk3.x, a3[rj][0]);
        a3[rj][1] = fmaf(t4.w, wk3.y, a3[rj][1]);
        a3[rj][2] = fmaf(t4.w, wk3.z, a3[rj][2]);
        a3[rj][3] = fmaf(t4.w, wk3.w, a3[rj][3]);
      }
    }
    float bias[4];
#pragma unroll
    for (int j = 0; j < 4; ++j) {
      const int o = lane * 4 + j;
      bias[j] = (o < 165) ? b3[o] : 0.f;
    }
#pragma unroll
    for (int rj = 0; rj < 8; ++rj) {
      const long rbase = (row0 + wv * 8 + rj) * 165L;
#pragma unroll
      for (int j = 0; j < 4; ++j) {
        const int o = lane * 4 + j;
        if (o < 165) out[rbase + o] = a3[rj][j] + bias[j];
      }
    }
  }
}

__global__ void finalize_k(const float* __restrict__ dsum, float* __restrict__ out) {
  if (threadIdx.x == 0 && blockIdx.x == 0)
    out[0] = *dsum * (1.0f / (4.0f * 65536.0f * 64.0f));
}

// ---------------- launch ----------------
extern "C" void kernel_launch(void* const* d_in, const int* in_sizes, int n_in, void* d_out,
                              int out_size, void* d_ws, size_t ws_size, hipStream_t stream) {
  (void)in_sizes; (void)n_in; (void)out_size; (void)ws_size;
  const float* x = (const float*)d_in[0];
  const float* enc_w1 = (const float*)d_in[1];
  const float* enc_b1 = (const float*)d_in[2];
  const float* enc_w2 = (const float*)d_in[3];
  const float* enc_b2 = (const float*)d_in[4];
  const float* enc_w3 = (const float*)d_in[5];
  const float* enc_b3 = (const float*)d_in[6];
  const float* enc_res_wa = (const float*)d_in[7];
  const float* enc_res_ba = (const float*)d_in[8];
  const float* enc_res_wb = (const float*)d_in[9];
  const float* enc_res_bb = (const float*)d_in[10];
  const float* q_w = (const float*)d_in[11];
  const float* q_b = (const float*)d_in[12];
  const float* embeds = (const float*)d_in[13];
  const float* dec_w1 = (const float*)d_in[14];
  const float* dec_b1 = (const float*)d_in[15];
  const float* dec_res_wa = (const float*)d_in[16];
  const float* dec_res_ba = (const float*)d_in[17];
  const float* dec_res_wb = (const float*)d_in[18];
  const float* dec_res_bb = (const float*)d_in[19];
  const float* dec_w2 = (const float*)d_in[20];
  const float* dec_b2 = (const float*)d_in[21];
  const float* dec_w3 = (const float*)d_in[22];
  const float* dec_b3 = (const float*)d_in[23];

  float* ws = (float*)d_ws;
  float* buf = ws;                          // [N][256]
  float* W = ws + (long)NROWS * SB;         // weight/codebook region

  float* dout = (float*)d_out;

  prep_k<<<(PREP_N + 255) / 256, 256, 0, stream>>>(enc_w1, enc_w2, enc_w3, q_w, dec_w1, dec_w2,
                                                   dec_w3, enc_res_wa, enc_res_wb, dec_res_wa,
                                                   dec_res_wb, embeds, W);

  const int GB = NROWS / 32;   // 2048 blocks (conv2, vq_fused, dec23)
  const int GR = NROWS / 64;   // 1024 blocks (conv6, resblock pairs)

  // encoder
  conv2_k<165, 168, 128, 2, 165, SB, false, true><<<GB, 256, 0, stream>>>(x, W + OFF_WT1, enc_b1, buf);
  conv6_k<128, 256, 256, SB, SB, false, true><<<GR, 512, 0, stream>>>(buf, W + OFF_WT2, enc_b2, buf);
  conv6_k<256, 256, 256, SB, SB, false, false><<<GR, 512, 0, stream>>>(buf, W + OFF_WT3, enc_b3, buf);
  resblock_pair_k<<<GR, 512, 0, stream>>>(buf, W + OFF_WAPE, enc_res_ba, W + OFF_WBTE, enc_res_bb);

  // q-conv + residual VQ + dec1 (fused)
  vq_fused_k<<<GB, 256, 0, stream>>>(buf, W + OFF_WTQ, q_b, embeds, W + OFF_EN2, W + OFF_ETG,
                                     W + OFF_DSUM, W + OFF_WTD1, dec_b1);

  // decoder
  resblock_pair_k<<<GR, 512, 0, stream>>>(buf, W + OFF_WAPD, dec_res_ba, W + OFF_WBTD, dec_res_bb);
  dec23_k<<<GB, 256, 0, stream>>>(buf, W + OFF_WTD2, dec_b2, W + OFF_WTD3, dec_b3, dout);

  finalize_k<<<1, 64, 0, stream>>>(W + OFF_DSUM, dout + (long)NROWS * 165);
}